// Round 3
// baseline (1037.288 us; speedup 1.0000x reference)
//
#include <hip/hip_runtime.h>

// Problem constants (X, Y: (64, 128, 64) fp32)
#define AA   64      // batch size
#define MM   128     // path length
#define DD   64      // feature dim
#define M1   127     // rows/cols of inc grid (MM-1)
#define TILE 32      // dX rows per LDS tile
#define WPB  4       // waves (pairs) per block

// ---------------------------------------------------------------------------
// init kernel: out[0] = mean((X[:,0,:] - Y[:,0,:])^2)
// ---------------------------------------------------------------------------
__global__ void init_out(const float* __restrict__ X, const float* __restrict__ Y,
                         float* __restrict__ out) {
    __shared__ float red[4];
    int tid = threadIdx.x;                    // 256 threads
    float acc = 0.f;
    for (int e = tid; e < AA * DD; e += 256) {
        int aa = e >> 6, d = e & 63;
        float df = X[aa * (MM * DD) + d] - Y[aa * (MM * DD) + d];
        acc = fmaf(df, df, acc);
    }
    #pragma unroll
    for (int off = 32; off > 0; off >>= 1) acc += __shfl_down(acc, off);
    if ((tid & 63) == 0) red[tid >> 6] = acc;
    __syncthreads();
    if (tid == 0) {
        float s = red[0] + red[1] + red[2] + red[3];
        out[0] = s / (float)(AA * DD);
    }
}

// ---------------------------------------------------------------------------
// PDE kernel: one wave per (a,b) pair; 4 pairs (same a) per block share the
// dX LDS tile. Lane l owns columns 2l, 2l+1 of the K row; dY columns live in
// VGPRs (128 regs/lane).
// Register history: (256,3) -> VGPR=84, 348 MB spill, 636 us.
//                   (256,2) -> VGPR=128, 84 MB spill, 679 us (allocator
//                   ignored the 256-reg headroom). (256,1) = cap 512, the
//                   only setting that fits dy0/dy1+state (~180 regs) w/o
//                   spill; HW occupancy still ~2-3 waves/SIMD from actual use.
//   delta[j] = K[j+1] - K[j] + K[j]*inc[i][j]
//   K_new    = [1, 1 + cumsum(delta)]
// ---------------------------------------------------------------------------
__global__ __launch_bounds__(256, 1)
void sig_pde_kernel(const float* __restrict__ X, const float* __restrict__ Y,
                    float* __restrict__ out) {
    const int tid  = threadIdx.x;
    const int lane = tid & 63;
    const int w    = tid >> 6;

    const int BPG = AA * (AA / WPB);          // 1024 blocks per gram
    int gid = blockIdx.x;
    const int g   = gid / BPG;                // 0: XX, 1: YY, 2: XY
    int rem = gid - g * BPG;
    const int a   = rem / (AA / WPB);
    const int bq  = rem - a * (AA / WPB);
    const int b   = bq * WPB + w;

    const float* P = (g == 1) ? Y : X;        // rows (i direction)
    const float* Q = (g == 0) ? X : Y;        // cols (j direction)
    const float wgt = (g == 2) ? (-2.0f / 4096.0f) : (1.0f / 4096.0f);

    __shared__ float dXs[2][TILE][DD];        // 16 KB, double-buffered

    // --- load this wave's two dY columns into registers (float4 quads) ----
    const int j0 = 2 * lane;                          // 0..126
    const int j1 = (j0 + 1 < M1) ? (j0 + 1) : (M1 - 1); // clamp lane 63 (unused)
    float4 dy0[DD / 4], dy1[DD / 4];
    const float* Qb = Q + b * (MM * DD);
    #pragma unroll
    for (int dd = 0; dd < DD / 4; ++dd) {
        float4 r0 = *(const float4*)(Qb + j0 * DD + 4 * dd);
        float4 r1 = *(const float4*)(Qb + (j0 + 1) * DD + 4 * dd);
        float4 rb = *(const float4*)(Qb + j1 * DD + 4 * dd);
        float4 r2 = *(const float4*)(Qb + (j1 + 1) * DD + 4 * dd);
        dy0[dd].x = r1.x - r0.x;  dy0[dd].y = r1.y - r0.y;
        dy0[dd].z = r1.z - r0.z;  dy0[dd].w = r1.w - r0.w;
        dy1[dd].x = r2.x - rb.x;  dy1[dd].y = r2.y - rb.y;
        dy1[dd].z = r2.z - rb.z;  dy1[dd].w = r2.w - rb.w;
    }

    // --- cooperative dX tile staging --------------------------------------
    const float* Pa = P + a * (MM * DD);
    auto stage = [&](int t0, int buf) {
        // TILE*DD = 2048 floats = 512 float4; 256 threads -> 2 each
        #pragma unroll
        for (int e = 0; e < 2; ++e) {
            int idx = e * 256 + tid;          // 0..511
            int i   = idx >> 4;               // row within tile
            int c   = idx & 15;               // float4 chunk
            int row = t0 + i;
            if (row < M1) {
                float4 lo = *(const float4*)(Pa + row * DD + 4 * c);
                float4 hi = *(const float4*)(Pa + (row + 1) * DD + 4 * c);
                float4 d4;
                d4.x = hi.x - lo.x; d4.y = hi.y - lo.y;
                d4.z = hi.z - lo.z; d4.w = hi.w - lo.w;
                *(float4*)(&dXs[buf][i][4 * c]) = d4;
            }
        }
    };

    float k0 = 1.0f, k1 = 1.0f;               // K[2l], K[2l+1] of current row
    int buf = 0;
    stage(0, 0);
    __syncthreads();

    for (int t0 = 0; t0 < M1; t0 += TILE) {
        if (t0 + TILE < M1) stage(t0 + TILE, buf ^ 1);
        const int rows = (M1 - t0 < TILE) ? (M1 - t0) : TILE;
        for (int ii = 0; ii < rows; ++ii) {
            const float4* xr4 = (const float4*)&dXs[buf][ii][0];
            // 4 accumulators: 2 per column chain to cover FMA latency
            float s0a = 0.f, s0b = 0.f, s1a = 0.f, s1b = 0.f;
            #pragma unroll
            for (int d4 = 0; d4 < DD / 8; ++d4) {
                float4 xA = xr4[2 * d4];
                float4 xB = xr4[2 * d4 + 1];
                float4 y0A = dy0[2 * d4], y0B = dy0[2 * d4 + 1];
                float4 y1A = dy1[2 * d4], y1B = dy1[2 * d4 + 1];
                s0a = fmaf(xA.x, y0A.x, s0a);
                s0a = fmaf(xA.y, y0A.y, s0a);
                s0a = fmaf(xA.z, y0A.z, s0a);
                s0a = fmaf(xA.w, y0A.w, s0a);
                s1a = fmaf(xA.x, y1A.x, s1a);
                s1a = fmaf(xA.y, y1A.y, s1a);
                s1a = fmaf(xA.z, y1A.z, s1a);
                s1a = fmaf(xA.w, y1A.w, s1a);
                s0b = fmaf(xB.x, y0B.x, s0b);
                s0b = fmaf(xB.y, y0B.y, s0b);
                s0b = fmaf(xB.z, y0B.z, s0b);
                s0b = fmaf(xB.w, y0B.w, s0b);
                s1b = fmaf(xB.x, y1B.x, s1b);
                s1b = fmaf(xB.y, y1B.y, s1b);
                s1b = fmaf(xB.z, y1B.z, s1b);
                s1b = fmaf(xB.w, y1B.w, s1b);
            }
            float s0 = s0a + s0b;
            float s1 = s1a + s1b;
            // delta pair for this lane
            float kp2 = __shfl_down(k0, 1);                    // K[2l+2]
            float e0  = k1 - k0 + k0 * s0;                     // delta[2l]
            float e1  = (lane < 63) ? (kp2 - k1 + k1 * s1) : 0.0f; // delta[2l+1]
            float t   = e0 + e1;
            // 64-lane inclusive scan of t
            float S = t;
            #pragma unroll
            for (int off = 1; off < 64; off <<= 1) {
                float n = __shfl_up(S, off);
                S += (lane >= off) ? n : 0.0f;
            }
            float Sp = __shfl_up(S, 1);                        // S_{l-1}
            k0 = (lane == 0) ? 1.0f : 1.0f + Sp;               // K_new[2l]
            k1 = 1.0f + S - e1;                                // K_new[2l+1]
        }
        __syncthreads();
        buf ^= 1;
    }

    // lane 63's k1 == K[127][127] for this pair
    if (lane == 63) atomicAdd(out, wgt * k1);
}

extern "C" void kernel_launch(void* const* d_in, const int* in_sizes, int n_in,
                              void* d_out, int out_size, void* d_ws, size_t ws_size,
                              hipStream_t stream) {
    const float* X = (const float*)d_in[0];
    const float* Y = (const float*)d_in[1];
    float* out = (float*)d_out;

    hipLaunchKernelGGL(init_out, dim3(1), dim3(256), 0, stream, X, Y, out);

    const int blocks = 3 * AA * (AA / WPB);   // 3072
    hipLaunchKernelGGL(sig_pde_kernel, dim3(blocks), dim3(256), 0, stream,
                       X, Y, out);
}

// Round 4
// 618.993 us; speedup vs baseline: 1.6758x; 1.6758x over previous
//
#include <hip/hip_runtime.h>

// Problem constants (X, Y: (64, 128, 64) fp32)
#define AA   64      // batch size
#define MM   128     // path length
#define DD   64      // feature dim
#define M1   127     // rows/cols of inc grid (MM-1)
#define TILE 32      // dX rows per LDS tile
#define WPB  4       // waves (pairs) per block

typedef float v2f __attribute__((ext_vector_type(2)));

// DPP helper: returns the DPP-moved value with 0 in invalid/masked lanes.
// CTRL: 0x111/0x112/0x114/0x118 = row_shr:1/2/4/8 (lane i reads lane i-N in
// its 16-row), 0x142/0x143 = row_bcast:15/31, 0x130 = wf_sl1 (lane i reads
// lane i+1), 0x138 = wf_sr1 (lane i reads lane i-1).
template <int CTRL, int RM>
__device__ __forceinline__ float dpp0(float x) {
    return __int_as_float(
        __builtin_amdgcn_update_dpp(0, __float_as_int(x), CTRL, RM, 0xF, false));
}

// ---------------------------------------------------------------------------
// init kernel: out[0] = mean((X[:,0,:] - Y[:,0,:])^2)
// ---------------------------------------------------------------------------
__global__ void init_out(const float* __restrict__ X, const float* __restrict__ Y,
                         float* __restrict__ out) {
    __shared__ float red[4];
    int tid = threadIdx.x;                    // 256 threads
    float acc = 0.f;
    for (int e = tid; e < AA * DD; e += 256) {
        int aa = e >> 6, d = e & 63;
        float df = X[aa * (MM * DD) + d] - Y[aa * (MM * DD) + d];
        acc = fmaf(df, df, acc);
    }
    #pragma unroll
    for (int off = 32; off > 0; off >>= 1) acc += __shfl_down(acc, off);
    if ((tid & 63) == 0) red[tid >> 6] = acc;
    __syncthreads();
    if (tid == 0) {
        float s = red[0] + red[1] + red[2] + red[3];
        out[0] = s / (float)(AA * DD);
    }
}

// ---------------------------------------------------------------------------
// PDE kernel: one wave per (a,b) pair; 4 pairs (same a) per block share the
// dX LDS tile. Lane l owns columns 2l, 2l+1 of the K row; dY columns live in
// VGPRs as interleaved float2 (v_pk_fma_f32 operands).
//   delta[j] = K[j+1] - K[j] + K[j]*inc[i][j]
//   K_new    = [1, 1 + cumsum(delta)]
// R3 lesson: ds_bpermute shfl scan = ~8x120cyc dependent latency per row ->
// latency-bound at low occupancy (1037 us). R4: DPP scan (VALU latency),
// pk_fma dot, and software-pipelined dot-vs-scan so the FMA block hides the
// scan chain even at 1 wave/SIMD.
// ---------------------------------------------------------------------------
__global__ __launch_bounds__(256, 1)
void sig_pde_kernel(const float* __restrict__ X, const float* __restrict__ Y,
                    float* __restrict__ out) {
    const int tid  = threadIdx.x;
    const int lane = tid & 63;
    const int w    = tid >> 6;

    const int BPG = AA * (AA / WPB);          // 1024 blocks per gram
    int gid = blockIdx.x;
    const int g   = gid / BPG;                // 0: XX, 1: YY, 2: XY
    int rem = gid - g * BPG;
    const int a   = rem / (AA / WPB);
    const int bq  = rem - a * (AA / WPB);
    const int b   = bq * WPB + w;

    const float* P = (g == 1) ? Y : X;        // rows (i direction)
    const float* Q = (g == 0) ? X : Y;        // cols (j direction)
    const float wgt = (g == 2) ? (-2.0f / 4096.0f) : (1.0f / 4096.0f);

    __shared__ float dXs[2][TILE][DD];        // 16 KB, double-buffered

    // --- load this wave's two dY columns into registers, interleaved ------
    // dyp[d] = { dY_{2l}[d], dY_{2l+1}[d] }  (128 VGPRs)
    const int j0 = 2 * lane;                          // 0..126
    const int j1 = (j0 + 1 < M1) ? (j0 + 1) : (M1 - 1); // clamp lane 63 (unused)
    v2f dyp[DD];
    const float* Qb = Q + b * (MM * DD);
    #pragma unroll
    for (int dd = 0; dd < DD / 4; ++dd) {
        float4 r0 = *(const float4*)(Qb + j0 * DD + 4 * dd);
        float4 r1 = *(const float4*)(Qb + (j0 + 1) * DD + 4 * dd);
        float4 rb = *(const float4*)(Qb + j1 * DD + 4 * dd);
        float4 r2 = *(const float4*)(Qb + (j1 + 1) * DD + 4 * dd);
        dyp[4*dd+0] = (v2f){r1.x - r0.x, r2.x - rb.x};
        dyp[4*dd+1] = (v2f){r1.y - r0.y, r2.y - rb.y};
        dyp[4*dd+2] = (v2f){r1.z - r0.z, r2.z - rb.z};
        dyp[4*dd+3] = (v2f){r1.w - r0.w, r2.w - rb.w};
    }

    // --- cooperative dX tile staging --------------------------------------
    const float* Pa = P + a * (MM * DD);
    auto stage = [&](int t0, int buf) {
        // TILE*DD = 2048 floats = 512 float4; 256 threads -> 2 each
        #pragma unroll
        for (int e = 0; e < 2; ++e) {
            int idx = e * 256 + tid;          // 0..511
            int i   = idx >> 4;               // row within tile
            int c   = idx & 15;               // float4 chunk
            int row = t0 + i;
            if (row < M1) {
                float4 lo = *(const float4*)(Pa + row * DD + 4 * c);
                float4 hi = *(const float4*)(Pa + (row + 1) * DD + 4 * c);
                float4 d4;
                d4.x = hi.x - lo.x; d4.y = hi.y - lo.y;
                d4.z = hi.z - lo.z; d4.w = hi.w - lo.w;
                *(float4*)(&dXs[buf][i][4 * c]) = d4;
            }
        }
    };

    // --- packed dot product: (<dX_row, dy0>, <dX_row, dy1>) ---------------
    auto dot = [&](int bsel, int row) -> v2f {
        const float* xr = &dXs[bsel][row][0];
        v2f aA = {0.f, 0.f}, aB = {0.f, 0.f}, aC = {0.f, 0.f}, aD = {0.f, 0.f};
        #pragma unroll
        for (int d = 0; d < DD; d += 4) {
            float4 x4 = *(const float4*)(xr + d);
            aA = __builtin_elementwise_fma((v2f){x4.x, x4.x}, dyp[d+0], aA);
            aB = __builtin_elementwise_fma((v2f){x4.y, x4.y}, dyp[d+1], aB);
            aC = __builtin_elementwise_fma((v2f){x4.z, x4.z}, dyp[d+2], aC);
            aD = __builtin_elementwise_fma((v2f){x4.w, x4.w}, dyp[d+3], aD);
        }
        return (aA + aB) + (aC + aD);
    };

    float k0 = 1.0f, k1 = 1.0f;               // K[2l], K[2l+1] of current row
    int buf = 0;
    stage(0, 0);
    __syncthreads();

    for (int t0 = 0; t0 < M1; t0 += TILE) {
        if (t0 + TILE < M1) stage(t0 + TILE, buf ^ 1);
        const int rows = (M1 - t0 < TILE) ? (M1 - t0) : TILE;
        v2f s_cur = dot(buf, 0);
        for (int ii = 0; ii < rows; ++ii) {
            // prefetch next row's dot (independent of K) — hides scan latency
            v2f s_nxt = dot(buf, (ii + 1 < rows) ? ii + 1 : ii);

            float s0 = s_cur.x, s1 = s_cur.y;
            float kp2 = dpp0<0x130, 0xF>(k0);            // K[2l+2] (wf_sl1)
            float e0  = k1 - k0 + k0 * s0;               // delta[2l]
            float e1  = (lane < 63) ? (kp2 - k1 + k1 * s1) : 0.0f; // delta[2l+1]
            // 64-lane inclusive DPP scan of (e0+e1)
            float S = e0 + e1;
            S += dpp0<0x111, 0xF>(S);                    // row_shr:1
            S += dpp0<0x112, 0xF>(S);                    // row_shr:2
            S += dpp0<0x114, 0xF>(S);                    // row_shr:4
            S += dpp0<0x118, 0xF>(S);                    // row_shr:8
            S += dpp0<0x142, 0xA>(S);                    // row_bcast:15
            S += dpp0<0x143, 0xC>(S);                    // row_bcast:31
            float Sp = dpp0<0x138, 0xF>(S);              // S_{l-1} (wf_sr1)
            k0 = 1.0f + Sp;                              // lane0: Sp=0 -> 1
            k1 = 1.0f + S - e1;

            s_cur = s_nxt;
        }
        __syncthreads();
        buf ^= 1;
    }

    // lane 63's k1 == K[127][127] for this pair
    if (lane == 63) atomicAdd(out, wgt * k1);
}

extern "C" void kernel_launch(void* const* d_in, const int* in_sizes, int n_in,
                              void* d_out, int out_size, void* d_ws, size_t ws_size,
                              hipStream_t stream) {
    const float* X = (const float*)d_in[0];
    const float* Y = (const float*)d_in[1];
    float* out = (float*)d_out;

    hipLaunchKernelGGL(init_out, dim3(1), dim3(256), 0, stream, X, Y, out);

    const int blocks = 3 * AA * (AA / WPB);   // 3072
    hipLaunchKernelGGL(sig_pde_kernel, dim3(blocks), dim3(256), 0, stream,
                       X, Y, out);
}

// Round 5
// 228.077 us; speedup vs baseline: 4.5480x; 2.7140x over previous
//
#include <hip/hip_runtime.h>

// Problem constants (X, Y: (64, 128, 64) fp32)
#define AA   64      // batch size
#define MM   128     // path length
#define DD   64      // feature dim
#define M1   127     // rows/cols of inc grid (MM-1)
#define WPB  4       // waves (pairs) per block, sharing b (dY in LDS)
#define SROW 16      // rows per MFMA strip
#define CSTR 132     // inc strip row stride in words (132%32=4 -> 2-way banks)

typedef float  f32x4 __attribute__((ext_vector_type(4)));
typedef short  bf8_t __attribute__((ext_vector_type(8)));   // 8 bf16 vals

// DPP helper: returns DPP-moved value, 0 in invalid/masked lanes.
template <int CTRL, int RM>
__device__ __forceinline__ float dpp0(float x) {
    return __int_as_float(
        __builtin_amdgcn_update_dpp(0, __float_as_int(x), CTRL, RM, 0xF, false));
}

__device__ __forceinline__ unsigned short bf16_rne(float v) {
    unsigned u = __float_as_uint(v);
    return (unsigned short)((u + 0x7FFFu + ((u >> 16) & 1u)) >> 16);
}
__device__ __forceinline__ float bf16_tof(unsigned short h) {
    return __uint_as_float(((unsigned)h) << 16);
}

// ---------------------------------------------------------------------------
// init: ws[0..63] = 0 (partial-sum slots), ws[64] = mean((X0-Y0)^2)
// ---------------------------------------------------------------------------
__global__ void init_out(const float* __restrict__ X, const float* __restrict__ Y,
                         float* __restrict__ ws) {
    __shared__ float red[4];
    int tid = threadIdx.x;                    // 256 threads
    if (tid < 64) ws[tid] = 0.0f;
    float acc = 0.f;
    for (int e = tid; e < AA * DD; e += 256) {
        int aa = e >> 6, d = e & 63;
        float df = X[aa * (MM * DD) + d] - Y[aa * (MM * DD) + d];
        acc = fmaf(df, df, acc);
    }
    #pragma unroll
    for (int off = 32; off > 0; off >>= 1) acc += __shfl_down(acc, off);
    if ((tid & 63) == 0) red[tid >> 6] = acc;
    __syncthreads();
    if (tid == 0) ws[64] = (red[0] + red[1] + red[2] + red[3]) / (float)(AA * DD);
}

// ---------------------------------------------------------------------------
// final: out[0] = ws[64] + sum(ws[0..63])
// ---------------------------------------------------------------------------
__global__ void final_sum(const float* __restrict__ ws, float* __restrict__ out) {
    int lane = threadIdx.x;                   // 64 threads
    float v = ws[lane];
    #pragma unroll
    for (int off = 32; off > 0; off >>= 1) v += __shfl_down(v, off);
    if (lane == 0) out[0] = v + ws[64];
}

// ---------------------------------------------------------------------------
// PDE kernel, MFMA inc + DPP scan.
//  - inc = dX . dY^T per pair via split-bf16 (hi/lo) 16x16x32 MFMA, 3 products
//    (hihi + hilo + lohi), fp32 accumulate: rel err ~2^-17 << 2% tolerance.
//  - B frags (dY): pre-swizzled hi/lo bf16 in LDS, fragment order
//    [t-tile][k-step][lane] so B load = 1 ds_read_b128. n = lane&15 + 16t,
//    k = (lane>>4)*8 + j  (mirror of verified A layout).
//  - A frags (dX): global->reg->split per strip; row m = lane&15,
//    k = (lane>>4)*8 + j.
//  - C/D: col = lane&15 (+16t), row = (lane>>4)*4 + reg  [m89-verified].
//  - C strips to per-wave LDS (stride CSTR=132: 2-way bank alias = free),
//    scan (R4-verified DPP prefix) reads inc[i][2l,2l+1] via ds_read_b64.
//  - col 127 zero-padded (e1 masked at lane 63); row 127 clamped (unread).
// ---------------------------------------------------------------------------
__global__ __launch_bounds__(256, 2)
void sig_pde_kernel(const float* __restrict__ X, const float* __restrict__ Y,
                    float* __restrict__ ws) {
    const int tid  = threadIdx.x;
    const int lane = tid & 63;
    const int w    = tid >> 6;

    const int gid = blockIdx.x;
    const int g   = gid >> 10;                // 0: XX, 1: YY, 2: XY (1024 blk/gram)
    const int rem = gid & 1023;
    const int b   = rem >> 4;                 // shared by the block's 4 waves
    const int a   = ((rem & 15) << 2) | w;

    const float* P = (g == 1) ? Y : X;        // rows (i / dX side)
    const float* Q = (g == 0) ? X : Y;        // cols (j / dY side)
    const float wgt = (g == 2) ? (-2.0f / 4096.0f) : (1.0f / 4096.0f);

    // LDS: B frags hi/lo (16 KB each) + per-wave inc strips (33 KB) + red
    __shared__ int4  bhiv[1024];              // [ (t*2+s)*64 + lane ] = 8 bf16
    __shared__ int4  blov[1024];
    __shared__ float incS[WPB][SROW * CSTR];  // 4 x 8448 B
    __shared__ float red4[WPB];

    // --- cooperative B fill: dY[j][d] split to hi/lo bf16, fragment order --
    {
        const float* Qb = Q + b * (MM * DD);
        for (int q = tid; q < 1024; q += 256) {
            int j  = q & 127;                 // frag n index (column of inc)
            int c  = q >> 7;                  // 0..7 ; d0 = 8c
            int d0 = c << 3;
            float v[8];
            if (j < M1) {
                float4 p0 = *(const float4*)(Qb + j * DD + d0);
                float4 p1 = *(const float4*)(Qb + j * DD + d0 + 4);
                float4 q0 = *(const float4*)(Qb + (j + 1) * DD + d0);
                float4 q1 = *(const float4*)(Qb + (j + 1) * DD + d0 + 4);
                v[0] = q0.x - p0.x; v[1] = q0.y - p0.y;
                v[2] = q0.z - p0.z; v[3] = q0.w - p0.w;
                v[4] = q1.x - p1.x; v[5] = q1.y - p1.y;
                v[6] = q1.z - p1.z; v[7] = q1.w - p1.w;
            } else {
                #pragma unroll
                for (int e = 0; e < 8; ++e) v[e] = 0.0f;
            }
            unsigned hs[8], ls[8];
            #pragma unroll
            for (int e = 0; e < 8; ++e) {
                unsigned short hb = bf16_rne(v[e]);
                hs[e] = hb;
                ls[e] = bf16_rne(v[e] - bf16_tof(hb));
            }
            // frag index: t = j>>4, s = c>>2, lane = (c&3)*16 + (j&15)
            int f = (((j >> 4) << 1) | (c >> 2)) * 64 + ((c & 3) << 4) + (j & 15);
            int4 hv, lv;
            hv.x = hs[0] | (hs[1] << 16);  hv.y = hs[2] | (hs[3] << 16);
            hv.z = hs[4] | (hs[5] << 16);  hv.w = hs[6] | (hs[7] << 16);
            lv.x = ls[0] | (ls[1] << 16);  lv.y = ls[2] | (ls[3] << 16);
            lv.z = ls[4] | (ls[5] << 16);  lv.w = ls[6] | (ls[7] << 16);
            bhiv[f] = hv;
            blov[f] = lv;
        }
    }
    __syncthreads();                          // only barrier before epilogue

    const float* Pa = P + a * (MM * DD);
    float* incW = &incS[w][0];

    // --- A loader: lane's 16 dX f32 values for one strip ------------------
    auto loadA = [&](int strip, float* dx) {
        int i = (strip << 4) + (lane & 15);
        if (i > 126) i = 126;                 // clamp (row 127 unread)
        const float* r0 = Pa + i * DD + ((lane >> 4) << 3);
        const float* r1 = r0 + DD;
        float4 a0 = *(const float4*)(r0);
        float4 a1 = *(const float4*)(r0 + 4);
        float4 a2 = *(const float4*)(r0 + 32);
        float4 a3 = *(const float4*)(r0 + 36);
        float4 c0 = *(const float4*)(r1);
        float4 c1 = *(const float4*)(r1 + 4);
        float4 c2 = *(const float4*)(r1 + 32);
        float4 c3 = *(const float4*)(r1 + 36);
        dx[0]  = c0.x - a0.x; dx[1]  = c0.y - a0.y;
        dx[2]  = c0.z - a0.z; dx[3]  = c0.w - a0.w;
        dx[4]  = c1.x - a1.x; dx[5]  = c1.y - a1.y;
        dx[6]  = c1.z - a1.z; dx[7]  = c1.w - a1.w;
        dx[8]  = c2.x - a2.x; dx[9]  = c2.y - a2.y;
        dx[10] = c2.z - a2.z; dx[11] = c2.w - a2.w;
        dx[12] = c3.x - a3.x; dx[13] = c3.y - a3.y;
        dx[14] = c3.z - a3.z; dx[15] = c3.w - a3.w;
    };

    float dxc[16], dxn[16];
    loadA(0, dxc);

    float k0 = 1.0f, k1 = 1.0f;               // K[2l], K[2l+1] of current row

    for (int strip = 0; strip < 8; ++strip) {
        // split A into hi/lo bf16 frags
        bf8_t Ah[2], Al[2];
        #pragma unroll
        for (int ks = 0; ks < 2; ++ks) {
            bf8_t h, l;
            #pragma unroll
            for (int j = 0; j < 8; ++j) {
                float v = dxc[ks * 8 + j];
                unsigned short hb = bf16_rne(v);
                h[j] = (short)hb;
                l[j] = (short)bf16_rne(v - bf16_tof(hb));
            }
            Ah[ks] = h; Al[ks] = l;
        }

        // MFMA: 8 col-tiles x 2 k-steps x 3 split-products
        f32x4 acc[8];
        #pragma unroll
        for (int t = 0; t < 8; ++t) acc[t] = (f32x4){0.f, 0.f, 0.f, 0.f};
        #pragma unroll
        for (int s = 0; s < 2; ++s) {
            #pragma unroll
            for (int t = 0; t < 8; ++t) {
                int fb = (((t << 1) | s) << 6) + lane;
                bf8_t bh = *(const bf8_t*)(bhiv + fb);
                bf8_t bl = *(const bf8_t*)(blov + fb);
                acc[t] = __builtin_amdgcn_mfma_f32_16x16x32_bf16(Ah[s], bh, acc[t], 0, 0, 0);
                acc[t] = __builtin_amdgcn_mfma_f32_16x16x32_bf16(Ah[s], bl, acc[t], 0, 0, 0);
                acc[t] = __builtin_amdgcn_mfma_f32_16x16x32_bf16(Al[s], bh, acc[t], 0, 0, 0);
            }
        }

        // C frags -> per-wave inc strip in LDS
        {
            int r0 = ((lane >> 4) << 2);
            int c0 = (lane & 15);
            #pragma unroll
            for (int t = 0; t < 8; ++t) {
                int col = (t << 4) + c0;
                incW[(r0 + 0) * CSTR + col] = acc[t][0];
                incW[(r0 + 1) * CSTR + col] = acc[t][1];
                incW[(r0 + 2) * CSTR + col] = acc[t][2];
                incW[(r0 + 3) * CSTR + col] = acc[t][3];
            }
        }

        // prefetch next strip's A (global, hides behind the scan)
        if (strip < 7) loadA(strip + 1, dxn);

        // scan this strip's rows (R4-verified DPP prefix recursion)
        const int rmax = (strip == 7) ? 15 : 16;
        for (int r = 0; r < rmax; ++r) {
            float2 sv = *(const float2*)(incW + r * CSTR + (lane << 1));
            float s0 = sv.x, s1 = sv.y;
            float kp2 = dpp0<0x130, 0xF>(k0);            // K[2l+2] (wf_sl1)
            float e0  = k1 - k0 + k0 * s0;               // delta[2l]
            float e1  = (lane < 63) ? (kp2 - k1 + k1 * s1) : 0.0f;
            float S = e0 + e1;
            S += dpp0<0x111, 0xF>(S);                    // row_shr:1
            S += dpp0<0x112, 0xF>(S);                    // row_shr:2
            S += dpp0<0x114, 0xF>(S);                    // row_shr:4
            S += dpp0<0x118, 0xF>(S);                    // row_shr:8
            S += dpp0<0x142, 0xA>(S);                    // row_bcast:15
            S += dpp0<0x143, 0xC>(S);                    // row_bcast:31
            float Sp = dpp0<0x138, 0xF>(S);              // S_{l-1} (wf_sr1)
            k0 = 1.0f + Sp;                              // lane0: Sp=0 -> 1
            k1 = 1.0f + S - e1;
        }

        #pragma unroll
        for (int e = 0; e < 16; ++e) dxc[e] = dxn[e];
    }

    // --- epilogue: block reduction, 1 atomic per block into 64 slots ------
    if (lane == 63) red4[w] = k1;             // K[127][127] of this pair
    __syncthreads();
    if (tid == 0) {
        float s = (red4[0] + red4[1] + red4[2] + red4[3]) * wgt;
        atomicAdd(&ws[gid & 63], s);
    }
}

extern "C" void kernel_launch(void* const* d_in, const int* in_sizes, int n_in,
                              void* d_out, int out_size, void* d_ws, size_t ws_size,
                              hipStream_t stream) {
    const float* X = (const float*)d_in[0];
    const float* Y = (const float*)d_in[1];
    float* out = (float*)d_out;
    float* ws  = (float*)d_ws;                // [0..63] partials, [64] msq term

    hipLaunchKernelGGL(init_out, dim3(1), dim3(256), 0, stream, X, Y, ws);

    const int blocks = 3 * 1024;              // 3 grams x 64 b x 16 a-groups
    hipLaunchKernelGGL(sig_pde_kernel, dim3(blocks), dim3(256), 0, stream,
                       X, Y, ws);

    hipLaunchKernelGGL(final_sum, dim3(1), dim3(64), 0, stream, ws, out);
}

// Round 6
// 160.903 us; speedup vs baseline: 6.4467x; 1.4175x over previous
//
#include <hip/hip_runtime.h>

// Problem constants (X, Y: (64, 128, 64) fp32)
#define AA   64
#define MM   128
#define DD   64
#define M1   127
#define CSTR 132                 // inc row stride (words); 132%32=4 -> 2-way banks (free)
#define NXY  1024                // XY gram blocks (all 4096 pairs, 4/block)
#define NTRI 544                 // triangle blocks per symmetric gram (a<=b)
#define NBLK (NXY + 2*NTRI)      // 2112
// ws layout: [0,4MB) frag regions {Xhi,Xlo,Yhi,Ylo} each 1MB =
//   path(64) x tile(8) x ks(2) x lane(64) x int4 ; [4MB,..) NBLK partials.
// Requires ws_size >= 4.2 MB.
#define REG_I4 65536             // int4 per 1MB region
#define PART_OFF (4u << 20)

typedef float f32x4 __attribute__((ext_vector_type(4)));
typedef short bf8_t __attribute__((ext_vector_type(8)));

template <int CTRL, int RM>
__device__ __forceinline__ float dpp0(float x) {
    return __int_as_float(
        __builtin_amdgcn_update_dpp(0, __float_as_int(x), CTRL, RM, 0xF, false));
}

__device__ __forceinline__ unsigned bf16_rne(float v) {
    unsigned u = __float_as_uint(v);
    return (u + 0x7FFFu + ((u >> 16) & 1u)) >> 16;
}
__device__ __forceinline__ float bf16_tof(unsigned h) {
    return __uint_as_float(h << 16);
}

// ---------------------------------------------------------------------------
// prep: build hi/lo bf16 fragments of dX/dY once, in MFMA fragment order.
// A-frag and B-frag layouts coincide (idx16=lane&15, k=(lane>>4)*8+j), so one
// array serves both operand sides. Row 127 clamped to 126: as A it's the
// never-scanned row 127; as B it's col 127 whose delta is masked at lane 63.
// ---------------------------------------------------------------------------
__global__ __launch_bounds__(256) void prep_frags(const float* __restrict__ X,
                                                  const float* __restrict__ Y,
                                                  int4* __restrict__ frag) {
    const int tid = threadIdx.x, lane = tid & 63, w = tid >> 6;
    const int W    = blockIdx.x * 4 + w;   // 0..1023
    const int inp  = W >> 9;               // 0: X, 1: Y
    const int p    = (W >> 3) & 63;
    const int tile = W & 7;
    const float* S = (inp ? Y : X) + p * (MM * DD);
    int i = tile * 16 + (lane & 15);
    if (i > 126) i = 126;
    const int d0 = (lane >> 4) << 3;

    int4* hi = frag + (inp * 2 + 0) * REG_I4;
    int4* lo = frag + (inp * 2 + 1) * REG_I4;
    const int base = p * 1024 + tile * 128 + lane;

    #pragma unroll
    for (int ks = 0; ks < 2; ++ks) {
        const float* r0 = S + i * DD + ks * 32 + d0;
        const float* r1 = r0 + DD;
        float4 a0 = *(const float4*)r0;
        float4 a1 = *(const float4*)(r0 + 4);
        float4 c0 = *(const float4*)r1;
        float4 c1 = *(const float4*)(r1 + 4);
        float v[8] = {c0.x - a0.x, c0.y - a0.y, c0.z - a0.z, c0.w - a0.w,
                      c1.x - a1.x, c1.y - a1.y, c1.z - a1.z, c1.w - a1.w};
        unsigned hs[8], ls[8];
        #pragma unroll
        for (int e = 0; e < 8; ++e) {
            hs[e] = bf16_rne(v[e]);
            ls[e] = bf16_rne(v[e] - bf16_tof(hs[e]));
        }
        int4 h, l;
        h.x = hs[0] | (hs[1] << 16); h.y = hs[2] | (hs[3] << 16);
        h.z = hs[4] | (hs[5] << 16); h.w = hs[6] | (hs[7] << 16);
        l.x = ls[0] | (ls[1] << 16); l.y = ls[2] | (ls[3] << 16);
        l.z = ls[4] | (ls[5] << 16); l.w = ls[6] | (ls[7] << 16);
        hi[base + ks * 64] = h;
        lo[base + ks * 64] = l;
    }
}

// ---------------------------------------------------------------------------
// PDE kernel. gid < 1024: XY gram (all pairs). Else triangle blocks for
// XX / YY (a<=b only; K_ab == K_ba by the symmetric recursion), weight 2
// off-diag, 1 diag, 0 for the ragged a>b waves.
// Per wave: 8 strips of (4 A-frag global loads | 48 MFMA | C->LDS | DPP scan).
// ---------------------------------------------------------------------------
__global__ __launch_bounds__(256, 2)
void sig_pde(const int4* __restrict__ frag, float* __restrict__ partials) {
    const int tid = threadIdx.x, lane = tid & 63, w = tid >> 6;
    const int gid = blockIdx.x;

    int a, b, ain, bin;
    float wgt;
    if (gid < NXY) {
        b = gid >> 4; a = ((gid & 15) << 2) | w;
        ain = 0; bin = 1;
        wgt = -2.0f / 4096.0f;
    } else {
        int t = gid - NXY;
        int inp = 0;
        if (t >= NTRI) { t -= NTRI; inp = 1; }
        int q = (int)((__builtin_sqrtf((float)(2 * t + 1)) - 1.0f) * 0.5f);
        while (2 * (q + 1) * (q + 2) <= t) ++q;
        while (q > 0 && 2 * q * (q + 1) > t) --q;
        int r  = t - 2 * q * (q + 1);
        int i  = r / (q + 1);
        int ag = r - i * (q + 1);
        b = 4 * q + i; a = 4 * ag + w;
        ain = bin = inp;
        wgt = (a < b) ? (2.0f / 4096.0f) : ((a == b) ? (1.0f / 4096.0f) : 0.0f);
    }

    __shared__ int4  Bh[1024], Bl[1024];     // 32 KB B fragments (hi/lo)
    __shared__ float incS[4][16 * CSTR];     // 33 KB per-wave inc strips
    __shared__ float red4[4];

    // --- stage this block's B fragment set (flat 32 KB copy, no converts) --
    {
        const int4* Bhg = frag + (bin * 2 + 0) * REG_I4 + b * 1024;
        const int4* Blg = frag + (bin * 2 + 1) * REG_I4 + b * 1024;
        #pragma unroll
        for (int c = 0; c < 4; ++c) {
            int idx = c * 256 + tid;
            Bh[idx] = Bhg[idx];
            Bl[idx] = Blg[idx];
        }
    }
    __syncthreads();

    const int4* Ahg = frag + (ain * 2 + 0) * REG_I4 + a * 1024;
    const int4* Alg = frag + (ain * 2 + 1) * REG_I4 + a * 1024;

    int4 Ah[2], Al[2], Ahn[2], Aln[2];
    Ah[0] = Ahg[lane];      Ah[1] = Ahg[64 + lane];
    Al[0] = Alg[lane];      Al[1] = Alg[64 + lane];

    float k0 = 1.0f, k1 = 1.0f;              // K[2l], K[2l+1] of current row
    float* incW = &incS[w][0];
    const int c2l = lane << 1;
    const int r0w = (lane >> 4) << 2, c0w = lane & 15;

    for (int strip = 0; strip < 8; ++strip) {
        if (strip < 7) {                     // prefetch next strip's A frags
            int off = (strip + 1) * 128 + lane;
            Ahn[0] = Ahg[off]; Ahn[1] = Ahg[off + 64];
            Aln[0] = Alg[off]; Aln[1] = Alg[off + 64];
        }

        f32x4 acc[8];
        #pragma unroll
        for (int t = 0; t < 8; ++t) acc[t] = (f32x4){0.f, 0.f, 0.f, 0.f};
        #pragma unroll
        for (int s = 0; s < 2; ++s) {
            bf8_t ah = __builtin_bit_cast(bf8_t, Ah[s]);
            bf8_t al = __builtin_bit_cast(bf8_t, Al[s]);
            #pragma unroll
            for (int t = 0; t < 8; ++t) {
                int fb = (t * 2 + s) * 64 + lane;
                bf8_t bh = *(const bf8_t*)&Bh[fb];
                bf8_t bl = *(const bf8_t*)&Bl[fb];
                acc[t] = __builtin_amdgcn_mfma_f32_16x16x32_bf16(ah, bh, acc[t], 0, 0, 0);
                acc[t] = __builtin_amdgcn_mfma_f32_16x16x32_bf16(ah, bl, acc[t], 0, 0, 0);
                acc[t] = __builtin_amdgcn_mfma_f32_16x16x32_bf16(al, bh, acc[t], 0, 0, 0);
            }
        }

        // C frags -> per-wave inc strip (2-way bank alias only; free)
        #pragma unroll
        for (int t = 0; t < 8; ++t) {
            float* pb = incW + r0w * CSTR + (t << 4) + c0w;
            pb[0]        = acc[t][0];
            pb[CSTR]     = acc[t][1];
            pb[2 * CSTR] = acc[t][2];
            pb[3 * CSTR] = acc[t][3];
        }

        // scan this strip's rows (R4/R5-verified DPP prefix recursion)
        const int rmax = (strip == 7) ? 15 : 16;
        for (int r = 0; r < rmax; ++r) {
            float2 sv = *(const float2*)(incW + r * CSTR + c2l);
            float s0 = sv.x, s1 = sv.y;
            float kp2 = dpp0<0x130, 0xF>(k0);            // K[2l+2] (wf_sl1)
            float e0  = k1 - k0 + k0 * s0;               // delta[2l]
            float e1  = (lane < 63) ? (kp2 - k1 + k1 * s1) : 0.0f;
            float S = e0 + e1;
            S += dpp0<0x111, 0xF>(S);                    // row_shr:1
            S += dpp0<0x112, 0xF>(S);                    // row_shr:2
            S += dpp0<0x114, 0xF>(S);                    // row_shr:4
            S += dpp0<0x118, 0xF>(S);                    // row_shr:8
            S += dpp0<0x142, 0xA>(S);                    // row_bcast:15
            S += dpp0<0x143, 0xC>(S);                    // row_bcast:31
            float Sp = dpp0<0x138, 0xF>(S);              // S_{l-1} (wf_sr1)
            k0 = 1.0f + Sp;                              // lane0: Sp=0 -> 1
            k1 = 1.0f + S - e1;
        }

        Ah[0] = Ahn[0]; Ah[1] = Ahn[1];
        Al[0] = Aln[0]; Al[1] = Aln[1];
    }

    if (lane == 63) red4[w] = wgt * k1;      // weighted K[127][127]
    __syncthreads();
    if (tid == 0)
        partials[gid] = red4[0] + red4[1] + red4[2] + red4[3];
}

// ---------------------------------------------------------------------------
// final: out[0] = sum(partials) + mean((X0-Y0)^2). Folds the msq term with
// the 1/4096 mean weight so one reduction suffices.
// ---------------------------------------------------------------------------
__global__ void final_sum(const float* __restrict__ X, const float* __restrict__ Y,
                          const float* __restrict__ partials, float* __restrict__ out) {
    __shared__ float red[4];
    int tid = threadIdx.x;                   // 256 threads
    float acc = 0.f;
    for (int e = tid; e < NBLK; e += 256) acc += partials[e];
    for (int e = tid; e < AA * DD; e += 256) {
        int aa = e >> 6, d = e & 63;
        float df = X[aa * (MM * DD) + d] - Y[aa * (MM * DD) + d];
        acc = fmaf(df * df, 1.0f / 4096.0f, acc);
    }
    #pragma unroll
    for (int off = 32; off > 0; off >>= 1) acc += __shfl_down(acc, off);
    if ((tid & 63) == 0) red[tid >> 6] = acc;
    __syncthreads();
    if (tid == 0) out[0] = red[0] + red[1] + red[2] + red[3];
}

extern "C" void kernel_launch(void* const* d_in, const int* in_sizes, int n_in,
                              void* d_out, int out_size, void* d_ws, size_t ws_size,
                              hipStream_t stream) {
    const float* X = (const float*)d_in[0];
    const float* Y = (const float*)d_in[1];
    float* out = (float*)d_out;
    int4*  frag = (int4*)d_ws;
    float* partials = (float*)((char*)d_ws + PART_OFF);

    hipLaunchKernelGGL(prep_frags, dim3(256), dim3(256), 0, stream, X, Y, frag);
    hipLaunchKernelGGL(sig_pde, dim3(NBLK), dim3(256), 0, stream, frag, partials);
    hipLaunchKernelGGL(final_sum, dim3(1), dim3(256), 0, stream, X, Y, partials, out);
}